// Round 13
// baseline (54.105 us; speedup 1.0000x reference)
//
#include <hip/hip_runtime.h>
#include <math.h>

// Problem constants: B=4, H=W=64, M=8, K=64
#define HW  4096
#define KK  64
#define WPB 4
#define BLK (WPB*64)

__device__ __forceinline__ unsigned umin32(unsigned a, unsigned b) { return a < b ? a : b; }

__device__ __forceinline__ float softplusf(float x) {
    return fmaxf(x, 0.0f) + log1pf(expf(-fabsf(x)));
}

// All-lane 64-wide u32 min. Idempotent overlapping network:
//   xor1, xor2 : DPP quad_perm (exact pair/quad combine)
//   ror4, ror8 : DPP row rotations (all lanes end with row-16 min)
//   xor16      : ds_swizzle 0x401F (verified r10)
//   xor32      : __shfl_xor width 64 (verified r1/r2)
// Builtin DPP (not raw asm): compiler fills the 2-cycle DPP hazards by
// interleaving the four concurrent chains instead of s_nop wave-stalls.
__device__ __forceinline__ unsigned allmin64(unsigned x) {
    unsigned y;
    y = (unsigned)__builtin_amdgcn_update_dpp((int)x,(int)x,0xB1, 0xF,0xF,false); x = umin32(x,y); // quad_perm [1,0,3,2] = xor1
    y = (unsigned)__builtin_amdgcn_update_dpp((int)x,(int)x,0x4E, 0xF,0xF,false); x = umin32(x,y); // quad_perm [2,3,0,1] = xor2
    y = (unsigned)__builtin_amdgcn_update_dpp((int)x,(int)x,0x124,0xF,0xF,false); x = umin32(x,y); // row_ror:4
    y = (unsigned)__builtin_amdgcn_update_dpp((int)x,(int)x,0x128,0xF,0xF,false); x = umin32(x,y); // row_ror:8
    y = (unsigned)__builtin_amdgcn_ds_swizzle((int)x, 0x401F);                    x = umin32(x,y); // xor16
    y = (unsigned)__shfl_xor((int)x, 32, 64);                                     x = umin32(x,y); // xor32
    return x;
}

__global__ __launch_bounds__(BLK) void assign_loss_kernel(
    const float*  __restrict__ ps,     // [B,HW,K]
    const float2* __restrict__ po,     // [B,HW,K] float2
    const int*    __restrict__ tgt,    // [B,512,512]
    float* __restrict__ pobj,
    float* __restrict__ ploc,
    int*   __restrict__ pnp)
{
    const int lane = threadIdx.x & 63;
    const int wib  = threadIdx.x >> 6;
    const int wid  = blockIdx.x * WPB + wib;   // (b,n) block; grid exact

    const int b = wid >> 12;
    const int n = wid & (HW - 1);
    const int h = n >> 6, w = n & 63;

    const int base = wid * KK + lane;
    const float  s  = ps[base];
    const float2 pv = po[base];
    const float po0 = pv.x, po1 = pv.y;

    const int ti = lane >> 3, tj = lane & 7;
    const int tv = tgt[((b * 512) + h * 8 + ti) * 512 + (w * 8 + tj)] > 0;
    const unsigned long long mask = __ballot(tv);
    const int npos = __popcll(mask);

    const float sig = 1.0f / (1.0f + expf(-s));
    const float cl  = sqrtf(sqrtf(1.0f - sig));   // order-equiv ^0.25 factor

    const unsigned lane_u = (unsigned)lane;
    unsigned dead = 0u;       // ~0 once this slot is assigned (key -> infinite)
    float locl = 0.0f;

    unsigned long long m = mask;
    while (m) {
        // ---- scalar extraction of up to 4 live cells (SALU, dual-issue) ---
        const int t0 = (int)__ffsll(m) - 1;  m &= m - 1;
        const bool h1 = (m != 0);
        const int t1 = (int)__ffsll(m) - 1;  m &= m - 1;
        const bool h2 = (m != 0);
        const int t2 = (int)__ffsll(m) - 1;  m &= m - 1;
        const bool h3 = (m != 0);
        const int t3 = (int)__ffsll(m) - 1;  m &= m - 1;

        // ---- per-cell cost keys (unique: lane id in low 6 bits) -----------
        float l0, l1, l2, l3;
        auto cellkey = [&](int t, float& l) -> unsigned {
            const float by = (float)(t >> 3) * 0.125f - 0.4375f;
            const float bx = (float)(t & 7)  * 0.125f - 0.4375f;
            l = fabsf(po0 - by) + fabsf(po1 - bx);
            return (__float_as_uint(l * cl) & ~63u) | lane_u;
        };
        const unsigned k0 = cellkey(t0, l0);
        const unsigned k1 = cellkey(t1, l1);
        const unsigned k2 = cellkey(t2, l2);
        const unsigned k3 = cellkey(t3, l3);

        const unsigned e0 =  k0 | dead;
        const unsigned e1 = (k1 | dead) | (h1 ? 0u : ~0u);
        const unsigned e2 = (k2 | dead) | (h2 ? 0u : ~0u);
        const unsigned e3 = (k3 | dead) | (h3 ? 0u : ~0u);

        // ---- 4 concurrent all-lane min chains (speculative: no exclusion
        //      of this traversal's earlier winners yet) ----------------------
        unsigned m0 = allmin64(e0);
        unsigned m1 = allmin64(e1);
        unsigned m2 = allmin64(e2);
        unsigned m3 = allmin64(e3);

        // ---- collision check (uniform scalars) ---------------------------
        const unsigned w0 = (unsigned)__builtin_amdgcn_readfirstlane((int)m0) & 63u;
        const unsigned w1 = (unsigned)__builtin_amdgcn_readfirstlane((int)m1) & 63u;
        const unsigned w2 = (unsigned)__builtin_amdgcn_readfirstlane((int)m2) & 63u;
        const unsigned w3 = (unsigned)__builtin_amdgcn_readfirstlane((int)m3) & 63u;
        const bool col =
            (h1 && (w1 == w0)) ||
            (h2 && ((w2 == w0) || (h1 && w2 == w1))) ||
            (h3 && ((w3 == w0) || (h1 && w3 == w1) || (h2 && w3 == w2)));

        if (col) {   // rare (~15%): exact serial redo with cumulative exclusion
            unsigned excl = (lane_u == w0) ? ~0u : 0u;
            m1 = allmin64(e1 | excl);
            const unsigned W1 = (unsigned)__builtin_amdgcn_readfirstlane((int)m1) & 63u;
            if (h1) excl |= (lane_u == W1) ? ~0u : 0u;
            m2 = allmin64(e2 | excl);
            const unsigned W2 = (unsigned)__builtin_amdgcn_readfirstlane((int)m2) & 63u;
            if (h2) excl |= (lane_u == W2) ? ~0u : 0u;
            m3 = allmin64(e3 | excl);
        }

        // ---- commit winners (clean-key compare: dead/gated lanes can't
        //      match; each lane wins at most one cell per traversal) --------
        const bool W0 = (k0 == m0);
        const bool W1b = (k1 == m1);
        const bool W2b = (k2 == m2);
        const bool W3b = (k3 == m3);
        locl = W0  ? l0 : locl;
        locl = W1b ? l1 : locl;
        locl = W2b ? l2 : locl;
        locl = W3b ? l3 : locl;
        dead = (W0 | W1b | W2b | W3b) ? ~0u : dead;
    }

    // ---- losses ---------------------------------------------------------
    const bool assigned = (dead != 0u);
    const float ce  = assigned ? softplusf(-s) : softplusf(s);
    const float p_t = assigned ? sig : (1.0f - sig);
    const float om  = 1.0f - p_t;
    float focal = ce * om * om * (assigned ? 0.6f : 0.4f);
    if (!assigned) locl = 0.0f;

    float fc = focal, lc = locl;
    #pragma unroll
    for (int o = 32; o; o >>= 1) {
        fc += __shfl_xor(fc, o, 64);
        lc += __shfl_xor(lc, o, 64);
    }

    __shared__ float sobj[WPB], sloc[WPB];
    __shared__ int   snp[WPB];
    if (lane == 0) { sobj[wib] = fc; sloc[wib] = lc; snp[wib] = npos; }
    __syncthreads();
    if (threadIdx.x == 0) {
        float o = 0.0f, l = 0.0f; int np = 0;
        #pragma unroll
        for (int q = 0; q < WPB; ++q) { o += sobj[q]; l += sloc[q]; np += snp[q]; }
        pobj[blockIdx.x] = o;
        ploc[blockIdx.x] = l;
        pnp [blockIdx.x] = np;
    }
}

__global__ __launch_bounds__(256) void finalize_kernel(
    const float* __restrict__ pobj,
    const float* __restrict__ ploc,
    const int*   __restrict__ pnp,
    int nb, float* __restrict__ out)
{
    __shared__ double so[256], sl[256];
    __shared__ long long sn[256];
    double o = 0.0, l = 0.0;
    long long np = 0;
    for (int i = threadIdx.x; i < nb; i += 256) {
        o  += (double)pobj[i];
        l  += (double)ploc[i];
        np += (long long)pnp[i];
    }
    so[threadIdx.x] = o; sl[threadIdx.x] = l; sn[threadIdx.x] = np;
    __syncthreads();
    for (int st = 128; st; st >>= 1) {
        if (threadIdx.x < st) {
            so[threadIdx.x] += so[threadIdx.x + st];
            sl[threadIdx.x] += sl[threadIdx.x + st];
            sn[threadIdx.x] += sn[threadIdx.x + st];
        }
        __syncthreads();
    }
    if (threadIdx.x == 0) {
        long long npos = sn[0] > 1 ? sn[0] : 1;
        out[0] = (float)((so[0] + 10.0 * sl[0]) / (double)npos);
    }
}

extern "C" void kernel_launch(void* const* d_in, const int* in_sizes, int n_in,
                              void* d_out, int out_size, void* d_ws, size_t ws_size,
                              hipStream_t stream) {
    const float*  ps  = (const float*)d_in[0];
    const float2* po  = (const float2*)d_in[1];
    const int*    tgt = (const int*)d_in[2];

    const int total_blocks = in_sizes[0] / KK;     // 16384
    const int nwg = total_blocks / WPB;            // 4096

    float* pobj = (float*)d_ws;
    float* ploc = pobj + nwg;
    int*   pnp  = (int*)(ploc + nwg);

    assign_loss_kernel<<<nwg, BLK, 0, stream>>>(ps, po, tgt, pobj, ploc, pnp);
    finalize_kernel<<<1, 256, 0, stream>>>(pobj, ploc, pnp, nwg, (float*)d_out);
}

// Round 14
// 47.948 us; speedup vs baseline: 1.1284x; 1.1284x over previous
//
#include <hip/hip_runtime.h>
#include <math.h>

// Problem constants: B=4, H=W=64, M=8, K=64
#define HW  4096
#define KK  64
#define BLK 256            // 4 waves per workgroup
#define BPW 2              // blocks per wave (full 64-lane chains, interleaved)

__device__ __forceinline__ float softplusf(float x) {
    return fmaxf(x, 0.0f) + log1pf(expf(-fabsf(x)));
}

// TWO independent 64-lane min chains, interleaved so each DPP's 2 required
// wait states are filled by the other chain's DPP + one s_nop 0 (instead of
// 7x s_nop 1 pure wave-stall in the single-chain version, r5/r6-verified).
// Controls identical to the r5/r6 chain (absmax 0.0): shr 1/2/4/8,
// bcast 15/31 -> full min in lane 63 of each chain.
__device__ __forceinline__ void wave_min2_u32(unsigned& a, unsigned& b) {
    asm("s_nop 1\n\t"
        "v_min_u32_dpp %0, %0, %0 row_shr:1  row_mask:0xf bank_mask:0xf\n\t"
        "v_min_u32_dpp %1, %1, %1 row_shr:1  row_mask:0xf bank_mask:0xf\n\t"
        "s_nop 0\n\t"
        "v_min_u32_dpp %0, %0, %0 row_shr:2  row_mask:0xf bank_mask:0xf\n\t"
        "v_min_u32_dpp %1, %1, %1 row_shr:2  row_mask:0xf bank_mask:0xf\n\t"
        "s_nop 0\n\t"
        "v_min_u32_dpp %0, %0, %0 row_shr:4  row_mask:0xf bank_mask:0xf\n\t"
        "v_min_u32_dpp %1, %1, %1 row_shr:4  row_mask:0xf bank_mask:0xf\n\t"
        "s_nop 0\n\t"
        "v_min_u32_dpp %0, %0, %0 row_shr:8  row_mask:0xf bank_mask:0xf\n\t"
        "v_min_u32_dpp %1, %1, %1 row_shr:8  row_mask:0xf bank_mask:0xf\n\t"
        "s_nop 0\n\t"
        "v_min_u32_dpp %0, %0, %0 row_bcast:15 row_mask:0xf bank_mask:0xf\n\t"
        "v_min_u32_dpp %1, %1, %1 row_bcast:15 row_mask:0xf bank_mask:0xf\n\t"
        "s_nop 0\n\t"
        "v_min_u32_dpp %0, %0, %0 row_bcast:31 row_mask:0xf bank_mask:0xf\n\t"
        "v_min_u32_dpp %1, %1, %1 row_bcast:31 row_mask:0xf bank_mask:0xf\n\t"
        "s_nop 1"
        : "+v"(a), "+v"(b));
}

// One wave serves blocks A=2wv and B=2wv+1; lane owns slot `lane` of each.
// Branchless 64-step raster greedy (r8-V3 structure, the only one measured
// at ~69 cyc/step); masks are wave-UNIFORM (SGPR) so gating is scalar.
// Key/dead-OR/tie-break machinery verified absmax 0.0 in r2-r12.
__global__ __launch_bounds__(BLK) void assign_loss_kernel(
    const float*  __restrict__ ps,     // [B,HW,K]
    const float2* __restrict__ po,     // [B,HW,K] float2
    const int*    __restrict__ tgt,    // [B,512,512]
    float* __restrict__ pobj,
    float* __restrict__ ploc,
    int*   __restrict__ pnp)
{
    const int lane = threadIdx.x & 63;
    const int wib  = threadIdx.x >> 6;
    const int wv   = blockIdx.x * 4 + wib;     // 8192 waves
    const int A    = wv * BPW;                 // block ids
    const int Bb   = A + 1;

    // block A coords / loads
    const int bA = A >> 12, nA = A & (HW - 1);
    const int hA = nA >> 6, wA = nA & 63;
    const int bB = Bb >> 12, nB = Bb & (HW - 1);
    const int hB = nB >> 6, wB = nB & 63;

    const float  sA  = ps[A  * KK + lane];
    const float  sB  = ps[Bb * KK + lane];
    const float2 pvA = po[A  * KK + lane];
    const float2 pvB = po[Bb * KK + lane];

    const int ti = lane >> 3, tj = lane & 7;
    const int tvA = tgt[((bA * 512) + hA * 8 + ti) * 512 + (wA * 8 + tj)] > 0;
    const int tvB = tgt[((bB * 512) + hB * 8 + ti) * 512 + (wB * 8 + tj)] > 0;
    const unsigned long long maskA = __ballot(tvA);   // uniform (SGPR)
    const unsigned long long maskB = __ballot(tvB);

    const float sigA = 1.0f / (1.0f + expf(-sA));
    const float sigB = 1.0f / (1.0f + expf(-sB));
    const float clA  = sqrtf(sqrtf(1.0f - sigA));   // order-equiv ^0.25
    const float clB  = sqrtf(sqrtf(1.0f - sigB));

    const unsigned lane_u = (unsigned)lane;
    unsigned deadA = 0u, deadB = 0u;
    float loclA = 0.0f, loclB = 0.0f;

    #pragma unroll 64
    for (int t = 0; t < 64; ++t) {
        // uniform scalar gates: dead target -> force key to 0xFFFFFFFF
        const unsigned gA = (maskA & (1ull << t)) ? 0u : ~0u;   // s_cselect
        const unsigned gB = (maskB & (1ull << t)) ? 0u : ~0u;
        const float by = (float)(t >> 3) * 0.125f - 0.4375f;    // literal
        const float bx = (float)(t & 7)  * 0.125f - 0.4375f;    // literal

        const float lA = fabsf(pvA.x - by) + fabsf(pvA.y - bx);
        const float lB = fabsf(pvB.x - by) + fabsf(pvB.y - bx);
        const unsigned kA = (__float_as_uint(lA * clA) & ~63u) | lane_u;
        const unsigned kB = (__float_as_uint(lB * clB) & ~63u) | lane_u;

        unsigned eA = (kA | deadA) | gA;
        unsigned eB = (kB | deadB) | gB;
        wave_min2_u32(eA, eB);                       // interleaved chains
        const unsigned mnA = (unsigned)__builtin_amdgcn_readlane((int)eA, 63);
        const unsigned mnB = (unsigned)__builtin_amdgcn_readlane((int)eB, 63);

        // clean-key compare: dead slots / gated cells can't match
        const bool wiA = (kA == mnA);
        const bool wiB = (kB == mnB);
        deadA = wiA ? ~0u : deadA;  loclA = wiA ? lA : loclA;
        deadB = wiB ? ~0u : deadB;  loclB = wiB ? lB : loclB;
    }

    // losses (slot `lane` of A and of B, both owned by this lane)
    float focal = 0.0f, locs = 0.0f;
    {
        const bool aA = (deadA != 0u);
        const float ceA = aA ? softplusf(-sA) : softplusf(sA);
        const float ptA = aA ? sigA : (1.0f - sigA);
        const float omA = 1.0f - ptA;
        focal += ceA * omA * omA * (aA ? 0.6f : 0.4f);
        locs  += aA ? loclA : 0.0f;
        const bool aB = (deadB != 0u);
        const float ceB = aB ? softplusf(-sB) : softplusf(sB);
        const float ptB = aB ? sigB : (1.0f - sigB);
        const float omB = 1.0f - ptB;
        focal += ceB * omB * omB * (aB ? 0.6f : 0.4f);
        locs  += aB ? loclB : 0.0f;
    }

    float fc = focal, lc = locs;
    #pragma unroll
    for (int o = 32; o; o >>= 1) {
        fc += __shfl_xor(fc, o, 64);
        lc += __shfl_xor(lc, o, 64);
    }
    const int cnt = __popcll(maskA) + __popcll(maskB);   // uniform

    __shared__ float sobj[4], sloc[4];
    __shared__ int   snp[4];
    if (lane == 0) { sobj[wib] = fc; sloc[wib] = lc; snp[wib] = cnt; }
    __syncthreads();
    if (threadIdx.x == 0) {
        float o = 0.0f, l = 0.0f; int np = 0;
        #pragma unroll
        for (int q = 0; q < 4; ++q) { o += sobj[q]; l += sloc[q]; np += snp[q]; }
        pobj[blockIdx.x] = o;
        ploc[blockIdx.x] = l;
        pnp [blockIdx.x] = np;
    }
}

__global__ __launch_bounds__(256) void finalize_kernel(
    const float* __restrict__ pobj,
    const float* __restrict__ ploc,
    const int*   __restrict__ pnp,
    int nb, float* __restrict__ out)
{
    __shared__ double so[256], sl[256];
    __shared__ long long sn[256];
    double o = 0.0, l = 0.0;
    long long np = 0;
    for (int i = threadIdx.x; i < nb; i += 256) {
        o  += (double)pobj[i];
        l  += (double)ploc[i];
        np += (long long)pnp[i];
    }
    so[threadIdx.x] = o; sl[threadIdx.x] = l; sn[threadIdx.x] = np;
    __syncthreads();
    for (int st = 128; st; st >>= 1) {
        if (threadIdx.x < st) {
            so[threadIdx.x] += so[threadIdx.x + st];
            sl[threadIdx.x] += sl[threadIdx.x + st];
            sn[threadIdx.x] += sn[threadIdx.x + st];
        }
        __syncthreads();
    }
    if (threadIdx.x == 0) {
        long long npos = sn[0] > 1 ? sn[0] : 1;
        out[0] = (float)((so[0] + 10.0 * sl[0]) / (double)npos);
    }
}

extern "C" void kernel_launch(void* const* d_in, const int* in_sizes, int n_in,
                              void* d_out, int out_size, void* d_ws, size_t ws_size,
                              hipStream_t stream) {
    const float*  ps  = (const float*)d_in[0];
    const float2* po  = (const float2*)d_in[1];
    const int*    tgt = (const int*)d_in[2];

    const int total_blocks = in_sizes[0] / KK;     // 16384
    const int nwg = total_blocks / (BPW * 4);      // 2048 (8 blocks per wg)

    float* pobj = (float*)d_ws;
    float* ploc = pobj + nwg;
    int*   pnp  = (int*)(ploc + nwg);

    assign_loss_kernel<<<nwg, BLK, 0, stream>>>(ps, po, tgt, pobj, ploc, pnp);
    finalize_kernel<<<1, 256, 0, stream>>>(pobj, ploc, pnp, nwg, (float*)d_out);
}